// Round 3
// baseline (111.942 us; speedup 1.0000x reference)
//
#include <hip/hip_runtime.h>
#include <hip/hip_bf16.h>
#include <cstdint>
#include <cstddef>

// ---------------------------------------------------------------------------
// KQV2DPixel: 1x1-conv projections + flash attention, B=8, Cin=64, Cm=32,
// N=4096. fp32 in/out. Split-bf16 QK^T (hi+lo), log2-domain online softmax,
// cvt_pk+permlane32_swap P-packing, K-split x ns with reduce kernel.
// R3: double-buffered LDS, ONE barrier per 64-key tile, early-issued staging
// loads (latency hidden under compute), s_setprio around MFMA clusters.
// ---------------------------------------------------------------------------

typedef __bf16 bf16x8 __attribute__((ext_vector_type(8)));
typedef float  f32x16 __attribute__((ext_vector_type(16)));
typedef float  f32x4  __attribute__((ext_vector_type(4)));

struct alignas(16) U4 { uint32_t w[4]; };

#define MFMA32(A, B, C) __builtin_amdgcn_mfma_f32_32x32x16_bf16((A), (B), (C), 0, 0, 0)

__device__ __forceinline__ uint16_t f2bf(float f) {
    uint32_t u = __builtin_bit_cast(uint32_t, f);
    u += 0x7fffu + ((u >> 16) & 1u);       // RNE
    return (uint16_t)(u >> 16);
}
__device__ __forceinline__ float bf2f(uint16_t h) {
    uint32_t u = ((uint32_t)h) << 16;
    return __builtin_bit_cast(float, u);
}
__device__ __forceinline__ uint32_t cvtpk(float lo, float hi) {
    uint32_t r;
    asm("v_cvt_pk_bf16_f32 %0, %1, %2" : "=v"(r) : "v"(lo), "v"(hi));
    return r;
}
__device__ __forceinline__ void swp(uint32_t& a, uint32_t& b) {
    asm("v_permlane32_swap_b32 %0, %1" : "+v"(a), "+v"(b));
}
__device__ __forceinline__ float ex2(float x) {   // 2^x
    float r;
    asm("v_exp_f32 %0, %1" : "=v"(r) : "v"(x));
    return r;
}
__device__ __forceinline__ float max3(float a, float b, float c) {
    return fmaxf(fmaxf(a, b), c);          // clang fuses to v_max3_f32
}

// ---------------------------------------------------------------------------
// Kernel 1: projections. grid 256 x 256. 2 threads/pixel (wave-uniform output
// half -> W streamed through SGPRs via scalar loads; no LDS). x in registers.
//   k,q: hi+lo bf16, [B][N][32]; q pre-scaled by log2(e).  v: bf16 [B][32][N].
// ---------------------------------------------------------------------------
__global__ __launch_bounds__(256) void proj_kernel(
    const float* __restrict__ x,
    const float* __restrict__ Wk, const float* __restrict__ bk,
    const float* __restrict__ Wq, const float* __restrict__ bq,
    const float* __restrict__ Wv, const float* __restrict__ bv,
    uint16_t* __restrict__ qhi, uint16_t* __restrict__ qlo,
    uint16_t* __restrict__ khi, uint16_t* __restrict__ klo,
    uint16_t* __restrict__ vt)
{
    const int tid  = threadIdx.x;
    const int lane = tid & 63;
    const int half = __builtin_amdgcn_readfirstlane((tid >> 6) & 1);  // wave-uniform
    const int pxl  = ((tid >> 7) << 6) + lane;   // 0..127
    const int b     = blockIdx.x >> 5;
    const int nbase = (blockIdx.x & 31) << 7;
    const int n     = nbase + pxl;
    const int ob    = half << 4;                 // output half base

    const float* xb = x + (size_t)b * 64 * 4096 + n;
    float xv[64];
    #pragma unroll
    for (int ci = 0; ci < 64; ++ci) xv[ci] = xb[(size_t)ci * 4096];

    #pragma unroll
    for (int pass = 0; pass < 3; ++pass) {
        const float* W    = pass == 0 ? Wk : (pass == 1 ? Wq : Wv);
        const float* bias = pass == 0 ? bk : (pass == 1 ? bq : bv);
        float acc[16];
        #pragma unroll
        for (int o = 0; o < 16; ++o) acc[o] = bias[ob + o];
        #pragma unroll
        for (int o = 0; o < 16; ++o) {
            const float* wr = W + (size_t)(ob + o) * 64;   // uniform -> s_load
            #pragma unroll
            for (int ci = 0; ci < 64; ++ci)
                acc[o] = fmaf(wr[ci], xv[ci], acc[o]);
        }
        if (pass == 2) {
            #pragma unroll
            for (int o = 0; o < 16; ++o)
                vt[((size_t)(b * 32 + ob + o)) * 4096 + n] = f2bf(acc[o]);
        } else {
            if (pass == 1) {
                #pragma unroll
                for (int o = 0; o < 16; ++o) acc[o] *= 1.44269504f;   // log2(e)
            }
            uint32_t hp[8], lp[8];
            #pragma unroll
            for (int j = 0; j < 8; ++j) {
                float a0 = acc[2 * j], a1 = acc[2 * j + 1];
                uint16_t h0 = f2bf(a0), h1 = f2bf(a1);
                hp[j] = (uint32_t)h0 | ((uint32_t)h1 << 16);
                uint16_t l0 = f2bf(a0 - bf2f(h0)), l1 = f2bf(a1 - bf2f(h1));
                lp[j] = (uint32_t)l0 | ((uint32_t)l1 << 16);
            }
            uint16_t* hd = (pass ? qhi : khi) + ((size_t)(b * 4096 + n)) * 32 + ob;
            uint16_t* ld = (pass ? qlo : klo) + ((size_t)(b * 4096 + n)) * 32 + ob;
            *(U4*)hd       = *(U4*)&hp[0];
            *(U4*)(hd + 8) = *(U4*)&hp[4];
            *(U4*)ld       = *(U4*)&lp[0];
            *(U4*)(ld + 8) = *(U4*)&lp[4];
        }
    }
}

// ---------------------------------------------------------------------------
// Kernel 2: flash attention with K-split. grid ns*256, 256 thr = 4 waves.
// b = blockIdx&7 (XCD-aligned). Per block: 128 q rows x (64/ns) 64-key tiles.
// Double-buffered LDS, one barrier/tile, staging loads issued before compute.
// ---------------------------------------------------------------------------
__global__ __launch_bounds__(256, 4) void attn_kernel(
    const uint16_t* __restrict__ qhi, const uint16_t* __restrict__ qlo,
    const uint16_t* __restrict__ khi, const uint16_t* __restrict__ klo,
    const uint16_t* __restrict__ vt, float* __restrict__ out,
    float* __restrict__ opart, float* __restrict__ mpart,
    float* __restrict__ lpart, int ns)
{
    __shared__ __align__(16) uint16_t lkh[2][64 * 40];   // K hi tiles, 80B rows
    __shared__ __align__(16) uint16_t lkl[2][64 * 40];   // K lo tiles
    __shared__ __align__(16) uint16_t lvt[2][32 * 72];   // V^T tiles, 144B rows

    const int blk    = blockIdx.x;
    const int b      = blk & 7;                 // XCD-aligned batch
    const int rest   = blk >> 3;
    const int qblk   = rest & 31;
    const int ksp    = rest >> 5;               // 0..ns-1
    const int ntiles = 64 / ns;
    const int kb0    = ksp * ntiles;
    const int kb1    = kb0 + ntiles;

    const int tid  = threadIdx.x;
    const int wv   = tid >> 6;
    const int lane = tid & 63;
    const int l31  = lane & 31;
    const int h32  = lane >> 5;
    const int qrow = qblk * 128 + wv * 32 + l31;

    bf16x8 qh0, qh1, ql0, ql1;
    {
        const uint16_t* r = qhi + ((size_t)(b * 4096 + qrow)) * 32;
        qh0 = __builtin_bit_cast(bf16x8, *(const U4*)(r + h32 * 8));
        qh1 = __builtin_bit_cast(bf16x8, *(const U4*)(r + 16 + h32 * 8));
        const uint16_t* r2 = qlo + ((size_t)(b * 4096 + qrow)) * 32;
        ql0 = __builtin_bit_cast(bf16x8, *(const U4*)(r2 + h32 * 8));
        ql1 = __builtin_bit_cast(bf16x8, *(const U4*)(r2 + 16 + h32 * 8));
    }

    f32x16 oacc;
    #pragma unroll
    for (int i = 0; i < 16; ++i) oacc[i] = 0.f;
    float m_run = -3.0e38f, l_run = 0.f;

    const U4* gkh = (const U4*)(khi + ((size_t)b * 4096) * 32);
    const U4* gkl = (const U4*)(klo + ((size_t)b * 4096) * 32);
    const uint16_t* gv = vt + ((size_t)b * 32) * 4096;

    // per-thread staging slots (same every tile)
    const int krow = tid >> 2, kqut = tid & 3;     // K: row, 16B quarter
    const int vrow = tid >> 3, voct = tid & 7;     // V: row, 16B eighth

    // ---- prologue: stage tile kb0 into buffer 0 ----
    {
        U4 a = gkh[kb0 * 256 + tid];
        U4 c = gkl[kb0 * 256 + tid];
        U4 v = *(const U4*)(gv + (size_t)vrow * 4096 + kb0 * 64 + voct * 8);
        *(U4*)((char*)lkh[0] + krow * 80 + kqut * 16) = a;
        *(U4*)((char*)lkl[0] + krow * 80 + kqut * 16) = c;
        *(U4*)((char*)lvt[0] + vrow * 144 + voct * 16) = v;
    }
    __syncthreads();

    for (int kb = kb0; kb < kb1; ++kb) {
        const int cur = kb & 1;
        const char* ckh = (const char*)lkh[cur];
        const char* ckl = (const char*)lkl[cur];
        const char* cvt_ = (const char*)lvt[cur];

        // ---- issue next tile's loads NOW (latency hides under compute) ----
        const bool have = (kb + 1 < kb1);
        U4 na, nc, nv;
        if (have) {
            na = gkh[(kb + 1) * 256 + tid];
            nc = gkl[(kb + 1) * 256 + tid];
            nv = *(const U4*)(gv + (size_t)vrow * 4096 + (kb + 1) * 64 + voct * 8);
        }

        // ---- QK^T, both 32-key halves ----
        f32x16 s0, s1;
        #pragma unroll
        for (int i = 0; i < 16; ++i) { s0[i] = 0.f; s1[i] = 0.f; }
        {
            const char* kr = ckh + l31 * 80 + h32 * 16;
            const char* lr = ckl + l31 * 80 + h32 * 16;
            bf16x8 a0 = __builtin_bit_cast(bf16x8, *(const U4*)kr);
            bf16x8 a1 = __builtin_bit_cast(bf16x8, *(const U4*)(kr + 32));
            bf16x8 b0 = __builtin_bit_cast(bf16x8, *(const U4*)lr);
            bf16x8 b1 = __builtin_bit_cast(bf16x8, *(const U4*)(lr + 32));
            const char* kr2 = ckh + (32 + l31) * 80 + h32 * 16;
            const char* lr2 = ckl + (32 + l31) * 80 + h32 * 16;
            bf16x8 c0 = __builtin_bit_cast(bf16x8, *(const U4*)kr2);
            bf16x8 c1 = __builtin_bit_cast(bf16x8, *(const U4*)(kr2 + 32));
            bf16x8 d0 = __builtin_bit_cast(bf16x8, *(const U4*)lr2);
            bf16x8 d1 = __builtin_bit_cast(bf16x8, *(const U4*)(lr2 + 32));
            __builtin_amdgcn_s_setprio(1);
            s0 = MFMA32(a0, qh0, s0);
            s0 = MFMA32(a1, qh1, s0);
            s1 = MFMA32(c0, qh0, s1);
            s1 = MFMA32(c1, qh1, s1);
            s0 = MFMA32(b0, qh0, s0);
            s0 = MFMA32(b1, qh1, s0);
            s1 = MFMA32(d0, qh0, s1);
            s1 = MFMA32(d1, qh1, s1);
            s0 = MFMA32(a0, ql0, s0);
            s0 = MFMA32(a1, ql1, s0);
            s1 = MFMA32(c0, ql0, s1);
            s1 = MFMA32(c1, ql1, s1);
            __builtin_amdgcn_s_setprio(0);
        }

        // ---- one online-softmax update per 64 keys (log2 domain) ----
        float mx[4];
        #pragma unroll
        for (int i = 0; i < 4; ++i)
            mx[i] = max3(max3(s0[i], s0[i + 4], s0[i + 8]),
                         max3(s0[i + 12], s1[i], s1[i + 4]),
                         fmaxf(s1[i + 8], s1[i + 12]));
        float pm = max3(max3(mx[0], mx[1], mx[2]), mx[3],
                        -3.0e38f);
        pm = fmaxf(pm, __shfl_xor(pm, 32));

        if (__any(pm > m_run)) {          // skip rescale when no row grew
            float mn  = fmaxf(m_run, pm);
            float scl = ex2(m_run - mn);
            l_run *= scl;
            #pragma unroll
            for (int i = 0; i < 16; ++i) oacc[i] *= scl;
            m_run = mn;
        }

        #pragma unroll
        for (int i = 0; i < 16; ++i) {
            s0[i] = ex2(s0[i] - m_run);
            s1[i] = ex2(s1[i] - m_run);
        }
        float sm[8];
        #pragma unroll
        for (int i = 0; i < 8; ++i)
            sm[i] = (s0[i] + s0[i + 8]) + (s1[i] + s1[i + 8]);
        #pragma unroll
        for (int i = 0; i < 4; ++i) sm[i] += sm[i + 4];
        float rs = (sm[0] + sm[2]) + (sm[1] + sm[3]);
        rs += __shfl_xor(rs, 32);
        l_run += rs;

        // ---- pack P -> 4 bf16x8 B-fragments (cvt_pk + permlane32_swap) ----
        U4 f1, f2, f3, f4;
        {
            uint32_t A = cvtpk(s0[0], s0[1]),  B = cvtpk(s0[4], s0[5]);   swp(A, B);
            uint32_t C = cvtpk(s0[2], s0[3]),  D = cvtpk(s0[6], s0[7]);   swp(C, D);
            f1.w[0] = A; f1.w[1] = C; f1.w[2] = B; f1.w[3] = D;
            A = cvtpk(s0[8], s0[9]);   B = cvtpk(s0[12], s0[13]);  swp(A, B);
            C = cvtpk(s0[10], s0[11]); D = cvtpk(s0[14], s0[15]);  swp(C, D);
            f2.w[0] = A; f2.w[1] = C; f2.w[2] = B; f2.w[3] = D;
            A = cvtpk(s1[0], s1[1]);   B = cvtpk(s1[4], s1[5]);    swp(A, B);
            C = cvtpk(s1[2], s1[3]);   D = cvtpk(s1[6], s1[7]);    swp(C, D);
            f3.w[0] = A; f3.w[1] = C; f3.w[2] = B; f3.w[3] = D;
            A = cvtpk(s1[8], s1[9]);   B = cvtpk(s1[12], s1[13]);  swp(A, B);
            C = cvtpk(s1[10], s1[11]); D = cvtpk(s1[14], s1[15]);  swp(C, D);
            f4.w[0] = A; f4.w[1] = C; f4.w[2] = B; f4.w[3] = D;
        }

        // ---- PV: O^T[c][q] += V^T * P^T ----
        {
            const char* vr = cvt_ + l31 * 144 + h32 * 16;
            bf16x8 v0 = __builtin_bit_cast(bf16x8, *(const U4*)vr);
            bf16x8 v1 = __builtin_bit_cast(bf16x8, *(const U4*)(vr + 32));
            bf16x8 v2 = __builtin_bit_cast(bf16x8, *(const U4*)(vr + 64));
            bf16x8 v3 = __builtin_bit_cast(bf16x8, *(const U4*)(vr + 96));
            __builtin_amdgcn_s_setprio(1);
            oacc = MFMA32(v0, __builtin_bit_cast(bf16x8, f1), oacc);
            oacc = MFMA32(v1, __builtin_bit_cast(bf16x8, f2), oacc);
            oacc = MFMA32(v2, __builtin_bit_cast(bf16x8, f3), oacc);
            oacc = MFMA32(v3, __builtin_bit_cast(bf16x8, f4), oacc);
            __builtin_amdgcn_s_setprio(0);
        }

        // ---- write next tile into the other buffer, single barrier ----
        if (have) {
            const int nxt = cur ^ 1;
            *(U4*)((char*)lkh[nxt] + krow * 80 + kqut * 16) = na;
            *(U4*)((char*)lkl[nxt] + krow * 80 + kqut * 16) = nc;
            *(U4*)((char*)lvt[nxt] + vrow * 144 + voct * 16) = nv;
        }
        __syncthreads();
    }

    // ---- epilogue ----
    if (ns == 1) {
        const float inv = 1.f / l_run;
        float* ob = out + ((size_t)b * 32) * 4096 + qrow;
        #pragma unroll
        for (int i = 0; i < 16; ++i) {
            int c = (i & 3) + 8 * (i >> 2) + 4 * h32;
            ob[(size_t)c * 4096] = oacc[i] * inv;
        }
    } else {
        float* op = opart + ((size_t)((ksp * 8 + b) * 32)) * 4096 + qrow;
        #pragma unroll
        for (int i = 0; i < 16; ++i) {
            int c = (i & 3) + 8 * (i >> 2) + 4 * h32;
            op[(size_t)c * 4096] = oacc[i];
        }
        if (h32 == 0) {
            mpart[((size_t)(ksp * 8 + b)) * 4096 + qrow] = m_run;
            lpart[((size_t)(ksp * 8 + b)) * 4096 + qrow] = l_run;
        }
    }
}

// ---------------------------------------------------------------------------
// Kernel 3: combine K-split partials. thread = (b, c, 4 pixels).
// ---------------------------------------------------------------------------
__global__ __launch_bounds__(256) void reduce_kernel(
    const float* __restrict__ opart, const float* __restrict__ mpart,
    const float* __restrict__ lpart, float* __restrict__ out, int ns)
{
    const int idx = blockIdx.x * 256 + threadIdx.x;   // 262144 quads
    const int nq  = idx & 1023;
    const int c   = (idx >> 10) & 31;
    const int b   = idx >> 15;
    const size_t noff = (size_t)nq * 4;

    f32x4 M;
    #pragma unroll
    for (int e = 0; e < 4; ++e) M[e] = -3.0e38f;
    for (int s = 0; s < ns; ++s) {
        f32x4 mm = *(const f32x4*)(mpart + ((size_t)(s * 8 + b)) * 4096 + noff);
        #pragma unroll
        for (int e = 0; e < 4; ++e) M[e] = fmaxf(M[e], mm[e]);
    }
    f32x4 L, O;
    #pragma unroll
    for (int e = 0; e < 4; ++e) { L[e] = 0.f; O[e] = 0.f; }
    for (int s = 0; s < ns; ++s) {
        f32x4 mm = *(const f32x4*)(mpart + ((size_t)(s * 8 + b)) * 4096 + noff);
        f32x4 ll = *(const f32x4*)(lpart + ((size_t)(s * 8 + b)) * 4096 + noff);
        f32x4 oo = *(const f32x4*)(opart + ((size_t)((s * 8 + b) * 32 + c)) * 4096 + noff);
        #pragma unroll
        for (int e = 0; e < 4; ++e) {
            float w = ex2(mm[e] - M[e]);
            L[e] += ll[e] * w;
            O[e] += oo[e] * w;
        }
    }
    f32x4 r;
    #pragma unroll
    for (int e = 0; e < 4; ++e) r[e] = O[e] / L[e];
    *(f32x4*)(out + ((size_t)(b * 32 + c)) * 4096 + noff) = r;
}

// ---------------------------------------------------------------------------
extern "C" void kernel_launch(void* const* d_in, const int* in_sizes, int n_in,
                              void* d_out, int out_size, void* d_ws, size_t ws_size,
                              hipStream_t stream)
{
    (void)in_sizes; (void)n_in; (void)out_size;
    const float* x  = (const float*)d_in[0];
    const float* Wk = (const float*)d_in[1];
    const float* bk = (const float*)d_in[2];
    const float* Wq = (const float*)d_in[3];
    const float* bq = (const float*)d_in[4];
    const float* Wv = (const float*)d_in[5];
    const float* bv = (const float*)d_in[6];
    float* out = (float*)d_out;

    char* ws = (char*)d_ws;
    const size_t SZ = (size_t)8 * 4096 * 32 * 2;   // 2 MB per bf16 buffer
    uint16_t* qhi = (uint16_t*)(ws);
    uint16_t* qlo = (uint16_t*)(ws + SZ);
    uint16_t* khi = (uint16_t*)(ws + 2 * SZ);
    uint16_t* klo = (uint16_t*)(ws + 3 * SZ);
    uint16_t* vt  = (uint16_t*)(ws + 4 * SZ);
    const size_t base = 5 * SZ;                    // 10 MB

    const size_t OB  = (size_t)8 * 32 * 4096 * 4;  // 4 MB per split (O^T)
    const size_t MB_ = (size_t)8 * 4096 * 4;       // 128 KB per split (m or l)
    int ns = 1;
    if      (ws_size >= base + 4 * (OB + 2 * MB_)) ns = 4;
    else if (ws_size >= base + 2 * (OB + 2 * MB_)) ns = 2;

    float* opart = (float*)(ws + base);
    float* mpart = (float*)(ws + base + (size_t)ns * OB);
    float* lpart = (float*)(ws + base + (size_t)ns * OB + (size_t)ns * MB_);

    proj_kernel<<<256, 256, 0, stream>>>(x, Wk, bk, Wq, bq, Wv, bv,
                                         qhi, qlo, khi, klo, vt);
    attn_kernel<<<ns * 256, 256, 0, stream>>>(qhi, qlo, khi, klo, vt, out,
                                              opart, mpart, lpart, ns);
    if (ns > 1)
        reduce_kernel<<<1024, 256, 0, stream>>>(opart, mpart, lpart, out, ns);
}